// Round 1
// baseline (183.505 us; speedup 1.0000x reference)
//
#include <hip/hip_runtime.h>

#define BATCH 4096
#define SEQ   128
#define DIN   64
#define DOUT  128
#define HID   32

// Workspace layout (floats):
//   [0,            DIN*HID)        : Wc[d][k] = (W_net @ W1)[d][k], 64x32 row-major
//   [DIN*HID,      DIN*HID + HID)  : bc[k]    = (b_net @ W1)[k] + b1[k]
//
// Key algebraic fold: ReLU sits AFTER layer 1, and row-selection is linear,
// so  feats @ W1 + b1 == x_row @ (Wn@W1) + (bn@W1 + b1).
// The DOUT=128 intermediate never needs to exist.

__global__ __launch_bounds__(256) void prep_fold_kernel(
    const float* __restrict__ Wn,   // (DIN, DOUT)
    const float* __restrict__ bn,   // (DOUT)
    const float* __restrict__ W1,   // (DOUT, HID)
    const float* __restrict__ b1,   // (HID)
    float*       __restrict__ ws)
{
    const int t = blockIdx.x * 256 + threadIdx.x;
    if (t < DIN * HID) {
        const int d = t >> 5;          // 0..63
        const int k = t & (HID - 1);   // 0..31
        float s = 0.0f;
        #pragma unroll 8
        for (int j = 0; j < DOUT; ++j)
            s = fmaf(Wn[d * DOUT + j], W1[j * HID + k], s);
        ws[t] = s;
    } else if (t < DIN * HID + HID) {
        const int k = t - DIN * HID;
        float s = b1[k];
        #pragma unroll 8
        for (int j = 0; j < DOUT; ++j)
            s = fmaf(bn[j], W1[j * HID + k], s);
        ws[t] = s;
    }
}

// One wave (64 lanes) per batch element. Barrier-free, LDS-free.
// Lanes 0..31 compute h[row0][k], lanes 32..63 compute h[row1][k].
__global__ __launch_bounds__(64) void fused_mlp_topk_kernel(
    const float* __restrict__ x,      // (B, S, DIN)
    const int*   __restrict__ mask,   // (B, S) int32 0/1
    const float* __restrict__ W2,     // (HID, 4)
    const float* __restrict__ b2,     // (4)
    const float* __restrict__ ws,     // folded weights
    float*       __restrict__ out)    // (B, 2, 4)
{
    const int b    = blockIdx.x;
    const int lane = threadIdx.x;   // 0..63

    // ---- find first two valid (mask=True) positions, stable order ----
    const int m0 = mask[b * SEQ + lane];
    const int m1 = mask[b * SEQ + 64 + lane];
    const unsigned long long bal0 = __ballot(m0 != 0);
    const unsigned long long bal1 = __ballot(m1 != 0);

    int i0 = 0, i1 = 0, cnt = 0;
    if (bal0) {
        i0 = __builtin_ctzll(bal0);
        unsigned long long rem = bal0 & (bal0 - 1ull);
        if (rem)       { i1 = __builtin_ctzll(rem);       cnt = 2; }
        else if (bal1) { i1 = 64 + __builtin_ctzll(bal1); cnt = 2; }
        else           { i1 = i0;                         cnt = 1; }
    } else if (bal1) {
        i0 = 64 + __builtin_ctzll(bal1);
        unsigned long long rem = bal1 & (bal1 - 1ull);
        if (rem) { i1 = 64 + __builtin_ctzll(rem); cnt = 2; }
        else     { i1 = i0;                        cnt = 1; }
    }
    // cnt==1: i1=i0 so preds1==preds0, matching the nv==1 "where" branch.

    const int r = lane >> 5;        // which selected row this half-wave owns
    const int k = lane & 31;        // hidden unit
    const int isel = r ? i1 : i0;

    // half-wave holds its row's 64 x-values in two regs (contiguous 128B loads)
    const size_t xrow = (size_t)b * SEQ * DIN + (size_t)isel * DIN;
    const float xlo = x[xrow + k];
    const float xhi = x[xrow + 32 + k];

    // ---- folded layer: h = relu(x_row @ Wc + bc) ----
    float h = ws[DIN * HID + k];    // bc[k]
    #pragma unroll 8
    for (int d = 0; d < 32; ++d) {
        const float xa = __shfl(xlo, d, 32);            // x_row[d] within half-wave
        const float xb = __shfl(xhi, d, 32);            // x_row[32+d]
        h = fmaf(xa, ws[d * HID + k], h);
        h = fmaf(xb, ws[(d + 32) * HID + k], h);
    }
    h = fmaxf(h, 0.0f);

    // ---- layer 2 via half-wave butterfly reduction ----
    float p0 = h * W2[k * 4 + 0];
    float p1 = h * W2[k * 4 + 1];
    float p2 = h * W2[k * 4 + 2];
    float p3 = h * W2[k * 4 + 3];
    #pragma unroll
    for (int off = 16; off > 0; off >>= 1) {
        p0 += __shfl_xor(p0, off, 32);
        p1 += __shfl_xor(p1, off, 32);
        p2 += __shfl_xor(p2, off, 32);
        p3 += __shfl_xor(p3, off, 32);
    }

    if (k < 4) {
        float p = (k == 0) ? p0 : (k == 1) ? p1 : (k == 2) ? p2 : p3;
        p += b2[k];
        out[b * 8 + r * 4 + k] = (cnt >= 1) ? p : 0.0f;
    }
}

extern "C" void kernel_launch(void* const* d_in, const int* in_sizes, int n_in,
                              void* d_out, int out_size, void* d_ws, size_t ws_size,
                              hipStream_t stream) {
    const float* x    = (const float*)d_in[0];
    const float* Wn   = (const float*)d_in[1];
    const float* bn   = (const float*)d_in[2];
    const float* W1   = (const float*)d_in[3];
    const float* b1   = (const float*)d_in[4];
    const float* W2   = (const float*)d_in[5];
    const float* b2   = (const float*)d_in[6];
    const int*   mask = (const int*)d_in[7];
    float* out = (float*)d_out;
    float* ws  = (float*)d_ws;

    // Fold Wn@W1 and bn@W1+b1 into workspace (2080 floats), then main kernel.
    prep_fold_kernel<<<(DIN * HID + HID + 255) / 256, 256, 0, stream>>>(Wn, bn, W1, b1, ws);
    fused_mlp_topk_kernel<<<BATCH, 64, 0, stream>>>(x, mask, W2, b2, ws, out);
}